// Round 5
// baseline (575.604 us; speedup 1.0000x reference)
//
#include <hip/hip_runtime.h>
#include <cstdint>

// Problem dims (fixed by reference)
#define BB 4
#define SS 2048
#define HH 1024
#define FF 4096
#define MM (BB * SS)   // 8192 tokens

typedef __attribute__((ext_vector_type(8))) short bf16x8;
typedef __attribute__((ext_vector_type(4))) float f32x4;

__device__ __forceinline__ unsigned short f2b(float f) {
  union { float f; unsigned u; } v; v.f = f;
  unsigned r = v.u + 0x7FFFu + ((v.u >> 16) & 1u);   // round-nearest-even
  return (unsigned short)(r >> 16);
}
__device__ __forceinline__ float b2f(unsigned short u) {
  union { unsigned u; float f; } v; v.u = ((unsigned)u) << 16; return v.f;
}

__device__ __forceinline__ void gld16(const void* g, void* l) {
  __builtin_amdgcn_global_load_lds(
      (const __attribute__((address_space(1))) void*)g,
      (__attribute__((address_space(3))) void*)l, 16, 0, 0);
}

#define FENCE asm volatile("" ::: "memory")
#define BAR do { FENCE; __builtin_amdgcn_s_barrier(); FENCE; } while (0)

// ---------- elementwise fp32 -> bf16 ----------
__global__ __launch_bounds__(256) void conv_f2b_kernel(
    const float* __restrict__ in, unsigned short* __restrict__ out, long n4) {
  long i = (long)blockIdx.x * 256 + threadIdx.x;
  if (i >= n4) return;
  const float4 f = ((const float4*)in)[i];
  ushort4 o;
  o.x = f2b(f.x); o.y = f2b(f.y); o.z = f2b(f.z); o.w = f2b(f.w);
  ((ushort4*)out)[i] = o;
}

// ---------- transpose fp32 [R,C] -> bf16 [C,R] ----------
__global__ __launch_bounds__(256) void transpose_f2b_kernel(
    const float* __restrict__ in, unsigned short* __restrict__ out, int R, int C) {
  __shared__ float t[32][33];
  int bc = blockIdx.x * 32;
  int br = blockIdx.y * 32;
  int x = threadIdx.x;   // 0..31
  int y0 = threadIdx.y;  // 0..7
#pragma unroll
  for (int yy = y0; yy < 32; yy += 8)
    t[yy][x] = in[(long)(br + yy) * C + bc + x];
  __syncthreads();
#pragma unroll
  for (int yy = y0; yy < 32; yy += 8)
    out[(long)(bc + yy) * R + br + x] = f2b(t[x][yy]);
}

// ---------- transpose bf16 [R,C] slice (ld_in given) -> bf16 [C,R] ----------
__global__ __launch_bounds__(256) void transpose_b2b_kernel(
    const unsigned short* __restrict__ in, long ldin,
    unsigned short* __restrict__ out, int R, int C) {
  __shared__ unsigned short t[32][33];
  int bc = blockIdx.x * 32;
  int br = blockIdx.y * 32;
  int x = threadIdx.x;
  int y0 = threadIdx.y;
#pragma unroll
  for (int yy = y0; yy < 32; yy += 8)
    t[yy][x] = in[(long)(br + yy) * ldin + bc + x];
  __syncthreads();
#pragma unroll
  for (int yy = y0; yy < 32; yy += 8)
    out[(long)(bc + yy) * R + br + x] = t[x][yy];
}

// ---------- concat 3 bias vectors [HH] -> [3*HH] ----------
__global__ __launch_bounds__(256) void concat3_kernel(
    const float* __restrict__ a, const float* __restrict__ b,
    const float* __restrict__ c, float* __restrict__ o) {
  int i = blockIdx.x * 256 + threadIdx.x;   // 0..3071
  float v = (i < HH) ? a[i] : (i < 2 * HH) ? b[i - HH] : c[i - 2 * HH];
  o[i] = v;
}

// ===== 256x256 pipelined GEMM helpers =====
__device__ __forceinline__ void rd_a(bf16x8 (&dst)[4][2],
                                     const unsigned short* lds, int base,
                                     int mbase, int fr, int frx, int cx) {
#pragma unroll
  for (int m = 0; m < 4; ++m)
#pragma unroll
    for (int s = 0; s < 2; ++s) {
      const int row = mbase + m * 16 + fr;
      const int st = ((s << 2) | cx) ^ frx;
      dst[m][s] = *(const bf16x8*)&lds[base + (row << 6) + (st << 3)];
    }
}
__device__ __forceinline__ void rd_b(bf16x8 (&dst)[2][2],
                                     const unsigned short* lds, int base,
                                     int rowbase, int fr, int frx, int cx) {
#pragma unroll
  for (int n = 0; n < 2; ++n)
#pragma unroll
    for (int s = 0; s < 2; ++s) {
      const int row = rowbase + n * 16 + fr;
      const int st = ((s << 2) | cx) ^ frx;
      dst[n][s] = *(const bf16x8*)&lds[base + (row << 6) + (st << 3)];
    }
}
template <int MQ, int NQ>
__device__ __forceinline__ void mm_block(f32x4 (&acc)[8][4],
                                         const bf16x8 (&af)[4][2],
                                         const bf16x8 (&bf)[2][2]) {
#pragma unroll
  for (int m = 0; m < 4; ++m)
#pragma unroll
    for (int n = 0; n < 2; ++n)
#pragma unroll
      for (int s = 0; s < 2; ++s)
        acc[MQ * 4 + m][NQ * 2 + n] = __builtin_amdgcn_mfma_f32_16x16x32_bf16(
            af[m][s], bf[n][s], acc[MQ * 4 + m][NQ * 2 + n], 0, 0, 0);
}

// ============ 256x256 pipelined GEMM, round 13 (race-free rebuild) ==========
// C[M,N] = A[M,K]*B[N,K]^T. 8 waves (2Mx4N), wave = 128x64 out, BK=64.
// LDS 128KB = 8 half-slots of 16KB: slot((buf<<2)|(isB<<1)|half).
// Half-slot: [128 rows][64 k] bf16, chunk perm st = c ^ (row&7) (verified
// conflict-free: SQ_LDS_BANK_CONFLICT=0 in r3). Staging via gld16 with
// inverse-permuted global source (rule 21).
//
// Round-4 failed (absmax 0.084): (1) post-MFMA reads placed BEFORE their
// vmcnt guard; (2) gld16 DMA into regions with other waves' ds_reads still
// outstanding (barriers don't drain lgkm). This rebuild derives every wait:
//
// Per tile u (buf p=u&1 holds tile u, pn holds u+1), MFMA order
// ph1:(a0,b0) ph2:(a1,b0) ph3:(a0,b1) ph4:(a1,b1) so each frag array is
// overwritten in-place only after its last use:
//  ph1: rd a1(u) [pre];  stB(p,0,u+2); BAR; MFMA; lgkm0;                BAR
//  ph2:                  stA(p,0,u+2); BAR; MFMA; vmcnt(6); rd b0(u+1); BAR
//  ph3:                  stB(p,1,u+2); BAR; MFMA; vmcnt(6); rd a0(u+1); BAR
//  ph4:                  stA(p,1,u+2); BAR; MFMA; rd b1(u+1); lgkm0;    BAR
// vmcnt proof (P(i,ph)=2 gld16): ph2's vmcnt(6) leaves {P(u-1,4),P(u,1),
// P(u,2)} -> P(u-1,3)=B-half1(u+1) landed before rd b0. ph3's vmcnt(6)
// leaves {P(u,1..3)} -> P(u-1,4)=A-half1(u+1) landed before rd a0 (wr=1
// waves read A-half1!). b1@ph4 needs P(u-1,3) (landed since ph2). a1@ph1
// needs P(u-2,4) (landed since ph3(u-1)). lgkm0 proof: stage into any
// region is preceded by a barrier behind which all waves drained reads of
// that region (A-halves: end-ph1 drain covers ph1 a1 + prev-ph3 a0 reads;
// B-halves: end-ph4 drain covers ph2/ph4 b reads). Prologue reads get
// their own lgkm0+BAR before the loop (they race with ph1(0)'s stB).
template <int OUT_MODE, int RELU, int HAS_BIAS, int HAS_RES, int SPLITK>
__device__ __forceinline__ void gemm256_body(
    const unsigned short* __restrict__ A, long lda, long sA,
    const unsigned short* __restrict__ Bm, long ldb, long sB,
    void* __restrict__ Cm, long ldc, long sC,
    unsigned short* __restrict__ C2,
    const float* __restrict__ bias,
    const float* __restrict__ res, long ldr,
    float scale, int K) {
  constexpr int SLOT = 8192;  // shorts per 16KB half-slot
  __shared__ __attribute__((aligned(16))) unsigned short lds[8 * SLOT];
  const int tid = threadIdx.x;
  const int lane = tid & 63;
  const int wave = tid >> 6;     // 0..7
  const int wr = wave >> 2;      // 0..1  M-half
  const int wc = wave & 3;       // 0..3  N-quarter
  const int z = blockIdx.z;

  // XCD-chunked bijective swizzle (T1/m204)
  const int nwg = (int)(gridDim.x * gridDim.y);
  const int wgid = (int)(blockIdx.y * gridDim.x + blockIdx.x);
  const int q = nwg >> 3, r = nwg & 7;
  const int xcd = wgid & 7, idx = wgid >> 3;
  const int swz = (xcd < r ? xcd * (q + 1) : r * (q + 1) + (xcd - r) * q) + idx;
  const long bm = (long)(swz / (int)gridDim.x) * 256;
  const long bn = (long)(swz % (int)gridDim.x) * 256;

  const int nt = K >> 6;   // K-tiles of 64 (16 or 32 here; always even, >=4)

  // staging thread map (inverse of the read-side permutation)
  const long srow = tid >> 3;                                // 0..63
  const long skb  = (long)(((tid & 7) ^ ((tid >> 3) & 7)) << 3);
  const unsigned short* Agl = A + (long)z * sA + (bm + srow) * lda + skb;
  const unsigned short* Bgl = Bm + (long)z * sB + (bn + srow) * ldb + skb;
  const long a64 = 64 * lda, b64 = 64 * ldb;
  unsigned short* lw = lds + tid * 8;

  auto stA = [&](int buf, int h, int kt) {
    const unsigned short* g = Agl + (long)h * 128 * lda + (long)kt * 64;
    unsigned short* l = lw + ((buf << 2) + h) * SLOT;
    gld16(g, l);
    gld16(g + a64, l + 4096);
  };
  auto stB = [&](int buf, int h, int kt) {
    const unsigned short* g = Bgl + (long)h * 128 * ldb + (long)kt * 64;
    unsigned short* l = lw + ((buf << 2) + 2 + h) * SLOT;
    gld16(g, l);
    gld16(g + b64, l + 4096);
  };

  // fragment read map
  const int fr = lane & 15;
  const int frx = fr & 7;
  const int cx = (lane >> 4) & 3;
  const int abase0 = wr * SLOT;                    // buf0 A base (wave's half)
  const int bbase0 = (2 + (wc >> 1)) * SLOT;       // buf0 B base (wave's half)
  const int brow = (wc & 1) * 64;

  f32x4 acc[8][4];
#pragma unroll
  for (int m = 0; m < 8; ++m)
#pragma unroll
    for (int n = 0; n < 4; ++n) acc[m][n] = (f32x4){0.f, 0.f, 0.f, 0.f};

  bf16x8 a0[4][2], a1[4][2], b0[2][2], b1[2][2];

  // prologue: stage tiles 0,1 (B0,A0,B1,A1 each = steady-state order);
  // vmcnt(8) = tile0 fully landed; read tile0 frags; drain before loop
  // (ph1(0)'s stB overwrites buf0 B half0).
  stB(0, 0, 0); stA(0, 0, 0); stB(0, 1, 0); stA(0, 1, 0);
  stB(1, 0, 1); stA(1, 0, 1); stB(1, 1, 1); stA(1, 1, 1);
  asm volatile("s_waitcnt vmcnt(8)" ::: "memory");
  BAR;
  rd_a(a0, lds, abase0, 0, fr, frx, cx);
  rd_b(b0, lds, bbase0, brow, fr, frx, cx);
  rd_b(b1, lds, bbase0, brow + 32, fr, frx, cx);
  asm volatile("s_waitcnt lgkmcnt(0)" ::: "memory");
  BAR;

  for (int u = 0; u < nt - 2; ++u) {
    const int p = u & 1;
    const int pn = p ^ 1;
    const int ba_c = (p << 2) * SLOT + abase0;       // this tile's A base
    const int ba_n = (pn << 2) * SLOT + abase0;      // next tile's A base
    const int bb_n = (pn << 2) * SLOT + bbase0;      // next tile's B base

    // ph1: rd a1(u); stage B0(u+2); MFMA qm0 x qn0; drain a1 reads
    rd_a(a1, lds, ba_c, 64, fr, frx, cx);
    stB(p, 0, u + 2);
    BAR;
    __builtin_amdgcn_s_setprio(1);
    mm_block<0, 0>(acc, a0, b0);
    __builtin_amdgcn_s_setprio(0);
    asm volatile("s_waitcnt lgkmcnt(0)" ::: "memory");
    BAR;

    // ph2: stage A0(u+2); MFMA qm1 x qn0 (b0 last use); rd b0(u+1)
    stA(p, 0, u + 2);
    BAR;
    __builtin_amdgcn_s_setprio(1);
    mm_block<1, 0>(acc, a1, b0);
    __builtin_amdgcn_s_setprio(0);
    asm volatile("s_waitcnt vmcnt(6)" ::: "memory");
    rd_b(b0, lds, bb_n, brow, fr, frx, cx);
    BAR;

    // ph3: stage B1(u+2); MFMA qm0 x qn1 (a0 last use); rd a0(u+1)
    stB(p, 1, u + 2);
    BAR;
    __builtin_amdgcn_s_setprio(1);
    mm_block<0, 1>(acc, a0, b1);
    __builtin_amdgcn_s_setprio(0);
    asm volatile("s_waitcnt vmcnt(6)" ::: "memory");
    rd_a(a0, lds, ba_n, 0, fr, frx, cx);
    BAR;

    // ph4: stage A1(u+2); MFMA qm1 x qn1 (a1,b1 last use); rd b1(u+1); drain
    stA(p, 1, u + 2);
    BAR;
    __builtin_amdgcn_s_setprio(1);
    mm_block<1, 1>(acc, a1, b1);
    __builtin_amdgcn_s_setprio(0);
    rd_b(b1, lds, bb_n, brow + 32, fr, frx, cx);
    asm volatile("s_waitcnt lgkmcnt(0)" ::: "memory");
    BAR;
  }

  // tail: tiles nt-2, nt-1 entirely from landed LDS (no stages, no barriers)
  asm volatile("s_waitcnt vmcnt(0)" ::: "memory");
  BAR;
  {
    const int pv = (nt - 2) & 1;
    const int ba_c = (pv << 2) * SLOT + abase0;
    const int ba_n = ((pv ^ 1) << 2) * SLOT + abase0;
    const int bb_n = ((pv ^ 1) << 2) * SLOT + bbase0;
    rd_a(a1, lds, ba_c, 64, fr, frx, cx);
    mm_block<0, 0>(acc, a0, b0);
    mm_block<1, 0>(acc, a1, b0);
    rd_b(b0, lds, bb_n, brow, fr, frx, cx);
    mm_block<0, 1>(acc, a0, b1);
    rd_a(a0, lds, ba_n, 0, fr, frx, cx);
    mm_block<1, 1>(acc, a1, b1);
    rd_b(b1, lds, bb_n, brow + 32, fr, frx, cx);
    rd_a(a1, lds, ba_n, 64, fr, frx, cx);
    mm_block<0, 0>(acc, a0, b0);
    mm_block<1, 0>(acc, a1, b0);
    mm_block<0, 1>(acc, a0, b1);
    mm_block<1, 1>(acc, a1, b1);
  }

  // epilogue: C/D layout col=lane&15, row=(lane>>4)*4+reg (m89-verified)
  const bool apply = !SPLITK || (z == 0);
  const long crow0 = bm + wr * 128 + ((lane >> 4) * 4);
  const long ccol0 = bn + wc * 64 + (lane & 15);
#pragma unroll
  for (int m = 0; m < 8; ++m) {
#pragma unroll
    for (int n = 0; n < 4; ++n) {
      const long col = ccol0 + n * 16;
      const float bv = (HAS_BIAS && apply) ? bias[col] : 0.f;
#pragma unroll
      for (int r = 0; r < 4; ++r) {
        const long row = crow0 + m * 16 + r;
        float v = acc[m][n][r] * scale + bv;
        if (HAS_RES) { if (apply) v += res[row * ldr + col]; }
        if (RELU) v = fmaxf(v, 0.f);
        const long idxc = (long)z * sC + row * ldc + col;
        if (OUT_MODE == 0 || OUT_MODE == 2) ((float*)Cm)[idxc] = v;
        if (OUT_MODE == 1) ((unsigned short*)Cm)[idxc] = f2b(v);
        if (OUT_MODE == 2) C2[idxc] = f2b(v);
      }
    }
  }
}

#define GEMM256_KERNEL(NAME, OM, RELU, HB, HR, SK)                           \
  __global__ __launch_bounds__(512, 2) void NAME(                            \
      const unsigned short* __restrict__ A, long lda, long sA,               \
      const unsigned short* __restrict__ Bm, long ldb, long sB,              \
      void* __restrict__ Cm, long ldc, long sC,                              \
      unsigned short* __restrict__ C2, const float* __restrict__ bias,       \
      const float* __restrict__ res, long ldr, float scale, int K) {         \
    gemm256_body<OM, RELU, HB, HR, SK>(A, lda, sA, Bm, ldb, sB, Cm, ldc,     \
                                       sC, C2, bias, res, ldr, scale, K);    \
  }
GEMM256_KERNEL(gemm_qkv,  1, 0, 1, 0, 0)
GEMM256_KERNEL(gemm_qk,   1, 0, 0, 1, 0)   // bf16 scores, mask as residual
GEMM256_KERNEL(gemm_ffn1, 1, 1, 1, 0, 0)
GEMM256_KERNEL(gemm_ffn2, 0, 0, 1, 1, 1)   // split-K=2 via blockIdx.z

// ---------- old 128xBN MFMA GEMM (kept for gemm_av, N=1024 small-grid) -----
template <int OUT_MODE, int RELU, int HAS_BIAS, int HAS_RES, int BN, int SPLITK>
__device__ __forceinline__ void gemm_bt_body(
    const unsigned short* __restrict__ A, long lda, long sA,
    const unsigned short* __restrict__ Bm, long ldb, long sB,
    void* __restrict__ Cm, long ldc, long sC,
    unsigned short* __restrict__ C2,
    const float* __restrict__ bias,
    const float* __restrict__ res, long ldr,
    float scale, int K) {
  constexpr int NW = BN / 32;
  constexpr int BSUB = BN * 32;
  __shared__ unsigned short As[2 * 128 * 32];
  __shared__ unsigned short Bs[2 * BSUB];
  const int tid = threadIdx.x;
  const int lane = tid & 63;
  const int wave = tid >> 6;
  const int z = blockIdx.z;

  const int nwg = (int)(gridDim.x * gridDim.y);
  const int wgid = (int)(blockIdx.y * gridDim.x + blockIdx.x);
  const int q = nwg >> 3, r = nwg & 7;
  const int xcd = wgid & 7, idx = wgid >> 3;
  const int swz = (xcd < r ? xcd * (q + 1) : r * (q + 1) + (xcd - r) * q) + idx;
  const int bxi = swz % (int)gridDim.x;
  const int byi = swz / (int)gridDim.x;
  const long bm = (long)byi * 128;
  const long bn = (long)bxi * BN;

  const long srow = tid >> 2;
  const long schunk = (long)((tid & 3) ^ ((tid >> 3) & 3));
  const unsigned short* Ap = A + (long)z * sA + (bm + srow) * lda + schunk * 8;
  const unsigned short* Bp = Bm + (long)z * sB + (bn + srow) * ldb + schunk * 8;
  unsigned short* asd = As + tid * 8;
  unsigned short* bsd = Bs + tid * 8;
  const long a64 = 64 * lda;
  const long b64 = 64 * ldb;

  f32x4 acc[4][NW];
#pragma unroll
  for (int i = 0; i < 4; ++i)
#pragma unroll
    for (int j = 0; j < NW; ++j) acc[i][j] = (f32x4){0.f, 0.f, 0.f, 0.f};

  const int mo = (wave >> 1) * 64;
  const int no = (wave & 1) * (BN / 2);
  const int fr = lane & 15;
  const int fc = (((lane >> 4) ^ ((lane >> 1) & 3))) * 8;

  for (int k0 = 0; k0 < K; k0 += 64) {
    __syncthreads();
    gld16(Ap + k0, asd);
    gld16(Ap + a64 + k0, asd + 2048);
    gld16(Ap + k0 + 32, asd + 4096);
    gld16(Ap + a64 + k0 + 32, asd + 6144);
    gld16(Bp + k0, bsd);
    if (BN == 128) gld16(Bp + b64 + k0, bsd + 2048);
    gld16(Bp + k0 + 32, bsd + BSUB);
    if (BN == 128) gld16(Bp + b64 + k0 + 32, bsd + BSUB + 2048);
    __syncthreads();
#pragma unroll
    for (int ks = 0; ks < 2; ++ks) {
      bf16x8 af[4], bfr[NW];
#pragma unroll
      for (int i = 0; i < 4; ++i)
        af[i] = *(const bf16x8*)&As[ks * 4096 + (mo + i * 16 + fr) * 32 + fc];
#pragma unroll
      for (int i = 0; i < NW; ++i)
        bfr[i] = *(const bf16x8*)&Bs[ks * BSUB + (no + i * 16 + fr) * 32 + fc];
#pragma unroll
      for (int mi = 0; mi < 4; ++mi)
#pragma unroll
        for (int ni = 0; ni < NW; ++ni)
          acc[mi][ni] = __builtin_amdgcn_mfma_f32_16x16x32_bf16(af[mi], bfr[ni], acc[mi][ni], 0, 0, 0);
    }
  }

  const bool apply = !SPLITK || (z == 0);
  const long crow = bm + mo + ((lane >> 4) * 4);
  const long ccol = bn + no + (lane & 15);
#pragma unroll
  for (int mi = 0; mi < 4; ++mi) {
#pragma unroll
    for (int ni = 0; ni < NW; ++ni) {
      const long col = ccol + ni * 16;
      const float bv = (HAS_BIAS && apply) ? bias[col] : 0.f;
#pragma unroll
      for (int r = 0; r < 4; ++r) {
        const long row = crow + mi * 16 + r;
        float v = acc[mi][ni][r] * scale + bv;
        if (HAS_RES) { if (apply) v += res[row * ldr + col]; }
        if (RELU) v = fmaxf(v, 0.f);
        const long idxc = (long)z * sC + row * ldc + col;
        if (OUT_MODE == 0 || OUT_MODE == 2) ((float*)Cm)[idxc] = v;
        if (OUT_MODE == 1) ((unsigned short*)Cm)[idxc] = f2b(v);
        if (OUT_MODE == 2) C2[idxc] = f2b(v);
      }
    }
  }
}

#define GEMM_KERNEL(NAME, OM, RELU, HB, HR, BN, SK)                          \
  __global__ __launch_bounds__(256) void NAME(                               \
      const unsigned short* __restrict__ A, long lda, long sA,               \
      const unsigned short* __restrict__ Bm, long ldb, long sB,              \
      void* __restrict__ Cm, long ldc, long sC,                              \
      unsigned short* __restrict__ C2, const float* __restrict__ bias,       \
      const float* __restrict__ res, long ldr, float scale, int K) {         \
    gemm_bt_body<OM, RELU, HB, HR, BN, SK>(A, lda, sA, Bm, ldb, sB, Cm, ldc, \
                                           sC, C2, bias, res, ldr, scale, K);\
  }
GEMM_KERNEL(gemm_av, 2, 0, 0, 0, 64, 0)   // N=1024: BN=64 -> 1024 blocks, 4/CU

// ---------- row softmax over S, bf16 in (mask pre-added) -> bf16 out ----------
__global__ __launch_bounds__(256) void softmax_kernel(
    const unsigned short* __restrict__ Sb, unsigned short* __restrict__ Ab) {
  const long row = blockIdx.x;          // 0..MM-1
  const int tid = threadIdx.x;
  const unsigned short* sr = Sb + row * SS + tid * 8;
  bf16x8 sv = *(const bf16x8*)sr;
  float v[8];
  float mx = -1e30f;
#pragma unroll
  for (int i = 0; i < 8; ++i) {
    v[i] = b2f((unsigned short)sv[i]);
    mx = fmaxf(mx, v[i]);
  }
#pragma unroll
  for (int off = 32; off > 0; off >>= 1) mx = fmaxf(mx, __shfl_xor(mx, off, 64));
  __shared__ float rm[4], rs[4];
  if ((tid & 63) == 0) rm[tid >> 6] = mx;
  __syncthreads();
  mx = fmaxf(fmaxf(rm[0], rm[1]), fmaxf(rm[2], rm[3]));
  float sum = 0.f;
#pragma unroll
  for (int i = 0; i < 8; ++i) { v[i] = __expf(v[i] - mx); sum += v[i]; }
#pragma unroll
  for (int off = 32; off > 0; off >>= 1) sum += __shfl_xor(sum, off, 64);
  if ((tid & 63) == 0) rs[tid >> 6] = sum;
  __syncthreads();
  sum = rs[0] + rs[1] + rs[2] + rs[3];
  const float inv = 1.f / sum;
  bf16x8 ov;
#pragma unroll
  for (int i = 0; i < 8; ++i) ov[i] = (short)f2b(v[i] * inv);
  *(bf16x8*)(Ab + row * SS + tid * 8) = ov;
}

// ---------- in-place LayerNorm over H=1024, fused split-K partial add ----------
__global__ __launch_bounds__(256) void layernorm_kernel(
    float* __restrict__ Y, const float* __restrict__ P1,
    const float* __restrict__ g, const float* __restrict__ b) {
  const long row = blockIdx.x;
  float* y = Y + row * HH;
  const float* p1 = P1 + row * HH;
  const int tid = threadIdx.x;
  float v[4];
  float s = 0.f, ss = 0.f;
#pragma unroll
  for (int i = 0; i < 4; ++i) {
    v[i] = y[tid + i * 256] + p1[tid + i * 256];
    s += v[i]; ss += v[i] * v[i];
  }
#pragma unroll
  for (int off = 32; off > 0; off >>= 1) {
    s += __shfl_xor(s, off, 64);
    ss += __shfl_xor(ss, off, 64);
  }
  __shared__ float r1[4], r2[4];
  if ((tid & 63) == 0) { r1[tid >> 6] = s; r2[tid >> 6] = ss; }
  __syncthreads();
  s = r1[0] + r1[1] + r1[2] + r1[3];
  ss = r2[0] + r2[1] + r2[2] + r2[3];
  const float mu = s * (1.f / HH);
  const float var = ss * (1.f / HH) - mu * mu;
  const float rinv = rsqrtf(var + 1e-5f);
#pragma unroll
  for (int i = 0; i < 4; ++i) {
    int c = tid + i * 256;
    y[c] = (v[i] - mu) * rinv * g[c] + b[c];
  }
}

extern "C" void kernel_launch(void* const* d_in, const int* in_sizes, int n_in,
                              void* d_out, int out_size, void* d_ws, size_t ws_size,
                              hipStream_t stream) {
  (void)in_sizes; (void)n_in; (void)out_size; (void)ws_size;
  const float* x     = (const float*)d_in[0];
  const float* mask  = (const float*)d_in[1];
  const float* qW    = (const float*)d_in[2];
  const float* qb    = (const float*)d_in[3];
  const float* kW    = (const float*)d_in[4];
  const float* kb    = (const float*)d_in[5];
  const float* vW    = (const float*)d_in[6];
  const float* vb    = (const float*)d_in[7];
  const float* w1    = (const float*)d_in[8];
  const float* b1    = (const float*)d_in[9];
  const float* w2    = (const float*)d_in[10];
  const float* b2    = (const float*)d_in[11];
  const float* gamma = (const float*)d_in[12];
  const float* beta  = (const float*)d_in[13];
  float* out = (float*)d_out;

  char* ws = (char*)d_ws;
  size_t o = 0;
  auto alloc = [&](size_t bytes) { void* p = ws + o; o += (bytes + 255) & ~(size_t)255; return p; };
  unsigned short* Wqkv = (unsigned short*)alloc((size_t)3 * HH * HH * 2); // [3072][1024] (N,K) bf16
  unsigned short* w1t  = (unsigned short*)alloc((size_t)FF * HH * 2);     // [F][H]
  unsigned short* w2t  = (unsigned short*)alloc((size_t)HH * FF * 2);     // [H][F]
  float*          qkvb = (float*)alloc((size_t)3 * HH * 4);               // concat bias
  unsigned short* xb   = (unsigned short*)alloc((size_t)MM * HH * 2);     // x bf16
  unsigned short* QKVb = (unsigned short*)alloc((size_t)MM * 3 * HH * 2); // [M,3072] bf16
  unsigned short* Vt   = (unsigned short*)alloc((size_t)HH * MM * 2);     // [H][M] V^T bf16
  float*          attnf= (float*)alloc((size_t)MM * HH * 4);              // attn fp32 (residual)
  unsigned short* attnb= (unsigned short*)alloc((size_t)MM * HH * 2);     // attn bf16
  unsigned short* Sb   = (unsigned short*)alloc((size_t)BB * SS * SS * 4);// scores bf16 (over-alloc; tail reused as hb)
  unsigned short* Ab   = (unsigned short*)alloc((size_t)BB * SS * SS * 2);
  unsigned short* hb   = Sb + (size_t)BB * SS * SS;  // [M,F] bf16; Sb dead by FFN1 time
  // ffn2 split-K partial #1: QKVb region is dead after gemm_qk/av (48 MB >= 32 MB)
  float*          part1= (float*)QKVb;

  const dim3 tb(32, 8);

  // 1. x -> bf16
  conv_f2b_kernel<<<MM * HH / 1024, 256, 0, stream>>>(x, xb, (long)MM * HH / 4);
  // 2. weight transposes (fp32 [K,N] -> bf16 [N,K]); QKV concatenated along N
  transpose_f2b_kernel<<<dim3(HH / 32, HH / 32), tb, 0, stream>>>(qW, Wqkv, HH, HH);
  transpose_f2b_kernel<<<dim3(HH / 32, HH / 32), tb, 0, stream>>>(kW, Wqkv + (size_t)HH * HH, HH, HH);
  transpose_f2b_kernel<<<dim3(HH / 32, HH / 32), tb, 0, stream>>>(vW, Wqkv + (size_t)2 * HH * HH, HH, HH);
  transpose_f2b_kernel<<<dim3(FF / 32, HH / 32), tb, 0, stream>>>(w1, w1t, HH, FF);
  transpose_f2b_kernel<<<dim3(HH / 32, FF / 32), tb, 0, stream>>>(w2, w2t, FF, HH);
  concat3_kernel<<<12, 256, 0, stream>>>(qb, kb, vb, qkvb);
  // 3. QKV = x * Wqkv^T + b, single 256^2 pipelined GEMM, bf16 out [M,3072]
  gemm_qkv<<<dim3(3 * HH / 256, MM / 256, 1), 512, 0, stream>>>(
      xb, HH, 0, Wqkv, HH, 0, QKVb, 3 * HH, 0, nullptr, qkvb, nullptr, 0, 1.f, HH);
  // 4. V^T (bf16 [M,1024] slice of QKVb -> bf16 [1024,M])
  transpose_b2b_kernel<<<dim3(HH / 32, MM / 32), tb, 0, stream>>>(
      QKVb + 2 * HH, 3 * HH, Vt, MM, HH);
  // 5. S = Q K^T / sqrt(H) + mask, batched over BB, bf16 out
  gemm_qk<<<dim3(SS / 256, SS / 256, BB), 512, 0, stream>>>(
      QKVb, 3 * HH, (long)SS * 3 * HH, QKVb + HH, 3 * HH, (long)SS * 3 * HH,
      Sb, SS, (long)SS * SS, nullptr, nullptr, mask, SS, 0.03125f, HH);
  // 6. A = softmax(S) -> bf16
  softmax_kernel<<<MM, 256, 0, stream>>>(Sb, Ab);
  // 7. attn = A V, batched; fp32 + bf16 dual output (old 128x64 kernel)
  gemm_av<<<dim3(HH / 64, SS / 128, BB), 256, 0, stream>>>(
      Ab, SS, (long)SS * SS, Vt, MM, SS, attnf, HH, (long)SS * HH,
      attnb, nullptr, nullptr, 0, 1.f, SS);
  // 8. h = relu(attn w1 + b1) -> bf16, 256^2 pipelined
  gemm_ffn1<<<dim3(FF / 256, MM / 256, 1), 512, 0, stream>>>(
      attnb, HH, 0, w1t, HH, 0, hb, FF, 0, nullptr, b1, nullptr, 0, 1.f, HH);
  // 9. y_partial = attn + h[:,z] w2[z,:] + b2 ; 256^2 pipelined, split-K=2
  gemm_ffn2<<<dim3(HH / 256, MM / 256, 2), 512, 0, stream>>>(
      hb, FF, (long)(FF / 2), w2t, FF, (long)(FF / 2),
      out, HH, (long)((float*)part1 - out),
      nullptr, b2, attnf, HH, 1.f, FF / 2);
  // 10. LayerNorm in place, fusing the split-K partial sum
  layernorm_kernel<<<MM, 256, 0, stream>>>(out, part1, gamma, beta);
}

// Round 6
// 552.625 us; speedup vs baseline: 1.0416x; 1.0416x over previous
//
#include <hip/hip_runtime.h>
#include <cstdint>

// Problem dims (fixed by reference)
#define BB 4
#define SS 2048
#define HH 1024
#define FF 4096
#define MM (BB * SS)   // 8192 tokens

typedef __attribute__((ext_vector_type(8))) short bf16x8;
typedef __attribute__((ext_vector_type(4))) float f32x4;

__device__ __forceinline__ unsigned short f2b(float f) {
  union { float f; unsigned u; } v; v.f = f;
  unsigned r = v.u + 0x7FFFu + ((v.u >> 16) & 1u);   // round-nearest-even
  return (unsigned short)(r >> 16);
}
__device__ __forceinline__ float b2f(unsigned short u) {
  union { unsigned u; float f; } v; v.u = ((unsigned)u) << 16; return v.f;
}

__device__ __forceinline__ void gld16(const void* g, void* l) {
  __builtin_amdgcn_global_load_lds(
      (const __attribute__((address_space(1))) void*)g,
      (__attribute__((address_space(3))) void*)l, 16, 0, 0);
}

#define FENCE asm volatile("" ::: "memory")
#define BAR do { FENCE; __builtin_amdgcn_s_barrier(); FENCE; } while (0)
#define SB __builtin_amdgcn_sched_barrier(0)

// ---------- elementwise fp32 -> bf16 ----------
__global__ __launch_bounds__(256) void conv_f2b_kernel(
    const float* __restrict__ in, unsigned short* __restrict__ out, long n4) {
  long i = (long)blockIdx.x * 256 + threadIdx.x;
  if (i >= n4) return;
  const float4 f = ((const float4*)in)[i];
  ushort4 o;
  o.x = f2b(f.x); o.y = f2b(f.y); o.z = f2b(f.z); o.w = f2b(f.w);
  ((ushort4*)out)[i] = o;
}

// ---------- transpose fp32 [R,C] -> bf16 [C,R] ----------
__global__ __launch_bounds__(256) void transpose_f2b_kernel(
    const float* __restrict__ in, unsigned short* __restrict__ out, int R, int C) {
  __shared__ float t[32][33];
  int bc = blockIdx.x * 32;
  int br = blockIdx.y * 32;
  int x = threadIdx.x;   // 0..31
  int y0 = threadIdx.y;  // 0..7
#pragma unroll
  for (int yy = y0; yy < 32; yy += 8)
    t[yy][x] = in[(long)(br + yy) * C + bc + x];
  __syncthreads();
#pragma unroll
  for (int yy = y0; yy < 32; yy += 8)
    out[(long)(bc + yy) * R + br + x] = f2b(t[x][yy]);
}

// ---------- transpose bf16 [R,C] slice (ld_in given) -> bf16 [C,R] ----------
__global__ __launch_bounds__(256) void transpose_b2b_kernel(
    const unsigned short* __restrict__ in, long ldin,
    unsigned short* __restrict__ out, int R, int C) {
  __shared__ unsigned short t[32][33];
  int bc = blockIdx.x * 32;
  int br = blockIdx.y * 32;
  int x = threadIdx.x;
  int y0 = threadIdx.y;
#pragma unroll
  for (int yy = y0; yy < 32; yy += 8)
    t[yy][x] = in[(long)(br + yy) * ldin + bc + x];
  __syncthreads();
#pragma unroll
  for (int yy = y0; yy < 32; yy += 8)
    out[(long)(bc + yy) * R + br + x] = t[x][yy];
}

// ---------- concat 3 bias vectors [HH] -> [3*HH] ----------
__global__ __launch_bounds__(256) void concat3_kernel(
    const float* __restrict__ a, const float* __restrict__ b,
    const float* __restrict__ c, float* __restrict__ o) {
  int i = blockIdx.x * 256 + threadIdx.x;   // 0..3071
  float v = (i < HH) ? a[i] : (i < 2 * HH) ? b[i - HH] : c[i - 2 * HH];
  o[i] = v;
}

// ============ 256x256 8-phase GEMM (r3 structure + sched_barrier pins) ======
// C[M,N] = A[M,K]*B[N,K]^T. 8 waves (2Mx4N), wave = 128x64 out, BK=64.
// LDS 128KB = 8 half-slots of 16KB: slot((buf<<2)|(isB<<1)|half).
// Half-slot: [128 rows][64 k] bf16, chunk perm st = c ^ (row&7) (verified
// conflict-free: SQ_LDS_BANK_CONFLICT=0). Staging via gld16 with
// inverse-permuted global source (rule 21).
//
// Round-6 change (single variable vs r3): __builtin_amdgcn_sched_barrier(0)
// immediately AFTER the pre-MFMA barrier and BEFORE the post-MFMA barrier.
// Theory: hipcc sinks the (plain C++) ds_reads toward their post-barrier
// uses and hoists register-only MFMAs past inline-asm barriers (rule #18),
// collapsing the phase overlap into a serial [BAR; reads; lgkm-drain; MFMA]
// loop -> measured MfmaUtil 22% vs predicted ~60%. Pins restore the written
// order: reads+stage issue before BAR (overlapping the PREVIOUS phase's
// in-flight MFMAs), MFMA stays after BAR. Memory ops are already ordered by
// the asm memory clobbers; pins only constrain register-only instrs.
//
// Schedule per tile u (buf p=u&1; correctness identical to r3, which passed):
//  ph1: rd a(qm0)+b0; stA(pn,0,u+1); BAR;SB; MFMA qm0xqn0; SB;BAR
//  ph2: rd b1;        stA(pn,1,u+1); BAR;SB; MFMA qm0xqn1; SB;BAR
//  ph3: rd a(qm1);    stB(p, 0,u+2); BAR;SB; MFMA qm1xqn0; SB;BAR
//  ph4:               stB(p, 1,u+2); BAR;SB; MFMA qm1xqn1; SB; vmcnt(4); BAR
// vmcnt(4) at end-ph4 leaves B0,B1(u+2) in flight, forces A(u+1) landed
// (4-phase lead) and transitively B(u+1) (staged tile u-1). Compiler-
// inserted lgkm waits cover read->MFMA deps (reads consumed same phase).
template <int OUT_MODE, int RELU, int HAS_BIAS, int HAS_RES, int SPLITK>
__device__ __forceinline__ void gemm256_body(
    const unsigned short* __restrict__ A, long lda, long sA,
    const unsigned short* __restrict__ Bm, long ldb, long sB,
    void* __restrict__ Cm, long ldc, long sC,
    unsigned short* __restrict__ C2,
    const float* __restrict__ bias,
    const float* __restrict__ res, long ldr,
    float scale, int K) {
  constexpr int SLOT = 8192;  // shorts per 16KB half-slot
  __shared__ __attribute__((aligned(16))) unsigned short lds[8 * SLOT];
  const int tid = threadIdx.x;
  const int lane = tid & 63;
  const int wave = tid >> 6;     // 0..7
  const int wr = wave >> 2;      // 0..1  M-half
  const int wc = wave & 3;       // 0..3  N-quarter
  const int z = blockIdx.z;

  // XCD-chunked bijective swizzle (T1/m204)
  const int nwg = (int)(gridDim.x * gridDim.y);
  const int wgid = (int)(blockIdx.y * gridDim.x + blockIdx.x);
  const int q = nwg >> 3, r = nwg & 7;
  const int xcd = wgid & 7, idx = wgid >> 3;
  const int swz = (xcd < r ? xcd * (q + 1) : r * (q + 1) + (xcd - r) * q) + idx;
  const long bm = (long)(swz / (int)gridDim.x) * 256;
  const long bn = (long)(swz % (int)gridDim.x) * 256;

  const int nt = K >> 6;   // K-tiles of 64 (>=16 for all our shapes)

  // staging thread map (inverse of the read-side permutation)
  const long srow = tid >> 3;                                // 0..63
  const long skb  = (long)(((tid & 7) ^ ((tid >> 3) & 7)) << 3);
  const unsigned short* Agl = A + (long)z * sA + (bm + srow) * lda + skb;
  const unsigned short* Bgl = Bm + (long)z * sB + (bn + srow) * ldb + skb;
  const long a64 = 64 * lda, b64 = 64 * ldb;
  unsigned short* lw = lds + tid * 8;

  auto stA = [&](int buf, int h, int kt) {
    const unsigned short* g = Agl + (long)h * 128 * lda + (long)kt * 64;
    unsigned short* l = lw + ((buf << 2) + h) * SLOT;
    gld16(g, l);
    gld16(g + a64, l + 4096);
  };
  auto stB = [&](int buf, int h, int kt) {
    const unsigned short* g = Bgl + (long)h * 128 * ldb + (long)kt * 64;
    unsigned short* l = lw + ((buf << 2) + 2 + h) * SLOT;
    gld16(g, l);
    gld16(g + b64, l + 4096);
  };

  // fragment read map
  const int fr = lane & 15;
  const int frx = fr & 7;
  const int cx = (lane >> 4) & 3;

  f32x4 acc[8][4];
#pragma unroll
  for (int m = 0; m < 8; ++m)
#pragma unroll
    for (int n = 0; n < 4; ++n) acc[m][n] = (f32x4){0.f, 0.f, 0.f, 0.f};

  // prologue: tile0 (all 4 halves) + B0,B1 of tile1; then counted wait
  stA(0, 0, 0); stA(0, 1, 0); stB(0, 0, 0); stB(0, 1, 0);
  stB(1, 0, 1); stB(1, 1, 1);
  asm volatile("s_waitcnt vmcnt(4)" ::: "memory");
  BAR;

  bf16x8 a_[4][2], b0_[2][2], b1_[2][2];

  for (int u = 0; u < nt; ++u) {
    const int p = u & 1;
    const int ba = ((p << 2) + wr) * SLOT;
    const int bb = ((p << 2) + 2 + (wc >> 1)) * SLOT;
    const int brow = (wc & 1) * 64;

    // ---- phase 1: A qm0 (8 reads) + B qn0 (4 reads); stage A0(u+1)
#pragma unroll
    for (int m = 0; m < 4; ++m)
#pragma unroll
      for (int s = 0; s < 2; ++s) {
        const int row = m * 16 + fr;
        const int st = ((s << 2) | cx) ^ frx;
        a_[m][s] = *(const bf16x8*)&lds[ba + (row << 6) + (st << 3)];
      }
#pragma unroll
    for (int n = 0; n < 2; ++n)
#pragma unroll
      for (int s = 0; s < 2; ++s) {
        const int row = brow + n * 16 + fr;
        const int st = ((s << 2) | cx) ^ frx;
        b0_[n][s] = *(const bf16x8*)&lds[bb + (row << 6) + (st << 3)];
      }
    if (u + 1 < nt) stA(p ^ 1, 0, u + 1);
    BAR;
    SB;
    __builtin_amdgcn_s_setprio(1);
#pragma unroll
    for (int m = 0; m < 4; ++m)
#pragma unroll
      for (int n = 0; n < 2; ++n)
#pragma unroll
        for (int s = 0; s < 2; ++s)
          acc[m][n] = __builtin_amdgcn_mfma_f32_16x16x32_bf16(
              a_[m][s], b0_[n][s], acc[m][n], 0, 0, 0);
    __builtin_amdgcn_s_setprio(0);
    SB;
    BAR;

    // ---- phase 2: B qn1 (4 reads); stage A1(u+1)
#pragma unroll
    for (int n = 0; n < 2; ++n)
#pragma unroll
      for (int s = 0; s < 2; ++s) {
        const int row = brow + (n + 2) * 16 + fr;
        const int st = ((s << 2) | cx) ^ frx;
        b1_[n][s] = *(const bf16x8*)&lds[bb + (row << 6) + (st << 3)];
      }
    if (u + 1 < nt) stA(p ^ 1, 1, u + 1);
    BAR;
    SB;
    __builtin_amdgcn_s_setprio(1);
#pragma unroll
    for (int m = 0; m < 4; ++m)
#pragma unroll
      for (int n = 0; n < 2; ++n)
#pragma unroll
        for (int s = 0; s < 2; ++s)
          acc[m][n + 2] = __builtin_amdgcn_mfma_f32_16x16x32_bf16(
              a_[m][s], b1_[n][s], acc[m][n + 2], 0, 0, 0);
    __builtin_amdgcn_s_setprio(0);
    SB;
    BAR;

    // ---- phase 3: A qm1 (8 reads); stage B0(u+2)
#pragma unroll
    for (int m = 0; m < 4; ++m)
#pragma unroll
      for (int s = 0; s < 2; ++s) {
        const int row = (m + 4) * 16 + fr;
        const int st = ((s << 2) | cx) ^ frx;
        a_[m][s] = *(const bf16x8*)&lds[ba + (row << 6) + (st << 3)];
      }
    if (u + 2 < nt) stB(p, 0, u + 2);
    BAR;
    SB;
    __builtin_amdgcn_s_setprio(1);
#pragma unroll
    for (int m = 0; m < 4; ++m)
#pragma unroll
      for (int n = 0; n < 2; ++n)
#pragma unroll
        for (int s = 0; s < 2; ++s)
          acc[m + 4][n] = __builtin_amdgcn_mfma_f32_16x16x32_bf16(
              a_[m][s], b0_[n][s], acc[m + 4][n], 0, 0, 0);
    __builtin_amdgcn_s_setprio(0);
    SB;
    BAR;

    // ---- phase 4: no reads; stage B1(u+2); checkpoint
    if (u + 2 < nt) stB(p, 1, u + 2);
    BAR;
    SB;
    __builtin_amdgcn_s_setprio(1);
#pragma unroll
    for (int m = 0; m < 4; ++m)
#pragma unroll
      for (int n = 0; n < 2; ++n)
#pragma unroll
        for (int s = 0; s < 2; ++s)
          acc[m + 4][n + 2] = __builtin_amdgcn_mfma_f32_16x16x32_bf16(
              a_[m][s], b1_[n][s], acc[m + 4][n + 2], 0, 0, 0);
    __builtin_amdgcn_s_setprio(0);
    SB;
    if (u + 1 < nt) {
      if (u + 2 < nt) asm volatile("s_waitcnt vmcnt(4)" ::: "memory");
      else            asm volatile("s_waitcnt vmcnt(0)" ::: "memory");
    }
    BAR;
  }

  // epilogue: C/D layout col=lane&15, row=(lane>>4)*4+reg (m89-verified)
  const bool apply = !SPLITK || (z == 0);
  const long crow0 = bm + wr * 128 + ((lane >> 4) * 4);
  const long ccol0 = bn + wc * 64 + (lane & 15);
#pragma unroll
  for (int m = 0; m < 8; ++m) {
#pragma unroll
    for (int n = 0; n < 4; ++n) {
      const long col = ccol0 + n * 16;
      const float bv = (HAS_BIAS && apply) ? bias[col] : 0.f;
#pragma unroll
      for (int r = 0; r < 4; ++r) {
        const long row = crow0 + m * 16 + r;
        float v = acc[m][n][r] * scale + bv;
        if (HAS_RES) { if (apply) v += res[row * ldr + col]; }
        if (RELU) v = fmaxf(v, 0.f);
        const long idxc = (long)z * sC + row * ldc + col;
        if (OUT_MODE == 0 || OUT_MODE == 2) ((float*)Cm)[idxc] = v;
        if (OUT_MODE == 1) ((unsigned short*)Cm)[idxc] = f2b(v);
        if (OUT_MODE == 2) C2[idxc] = f2b(v);
      }
    }
  }
}

#define GEMM256_KERNEL(NAME, OM, RELU, HB, HR, SK)                           \
  __global__ __launch_bounds__(512, 2) void NAME(                            \
      const unsigned short* __restrict__ A, long lda, long sA,               \
      const unsigned short* __restrict__ Bm, long ldb, long sB,              \
      void* __restrict__ Cm, long ldc, long sC,                              \
      unsigned short* __restrict__ C2, const float* __restrict__ bias,       \
      const float* __restrict__ res, long ldr, float scale, int K) {         \
    gemm256_body<OM, RELU, HB, HR, SK>(A, lda, sA, Bm, ldb, sB, Cm, ldc,     \
                                       sC, C2, bias, res, ldr, scale, K);    \
  }
GEMM256_KERNEL(gemm_qkv,  1, 0, 1, 0, 0)
GEMM256_KERNEL(gemm_qk,   1, 0, 0, 1, 0)   // bf16 scores, mask as residual
GEMM256_KERNEL(gemm_ffn1, 1, 1, 1, 0, 0)
GEMM256_KERNEL(gemm_ffn2, 0, 0, 1, 1, 1)   // split-K=2 via blockIdx.z

// ---------- old 128xBN MFMA GEMM (kept for gemm_av, N=1024 small-grid) -----
template <int OUT_MODE, int RELU, int HAS_BIAS, int HAS_RES, int BN, int SPLITK>
__device__ __forceinline__ void gemm_bt_body(
    const unsigned short* __restrict__ A, long lda, long sA,
    const unsigned short* __restrict__ Bm, long ldb, long sB,
    void* __restrict__ Cm, long ldc, long sC,
    unsigned short* __restrict__ C2,
    const float* __restrict__ bias,
    const float* __restrict__ res, long ldr,
    float scale, int K) {
  constexpr int NW = BN / 32;
  constexpr int BSUB = BN * 32;
  __shared__ unsigned short As[2 * 128 * 32];
  __shared__ unsigned short Bs[2 * BSUB];
  const int tid = threadIdx.x;
  const int lane = tid & 63;
  const int wave = tid >> 6;
  const int z = blockIdx.z;

  const int nwg = (int)(gridDim.x * gridDim.y);
  const int wgid = (int)(blockIdx.y * gridDim.x + blockIdx.x);
  const int q = nwg >> 3, r = nwg & 7;
  const int xcd = wgid & 7, idx = wgid >> 3;
  const int swz = (xcd < r ? xcd * (q + 1) : r * (q + 1) + (xcd - r) * q) + idx;
  const int bxi = swz % (int)gridDim.x;
  const int byi = swz / (int)gridDim.x;
  const long bm = (long)byi * 128;
  const long bn = (long)bxi * BN;

  const long srow = tid >> 2;
  const long schunk = (long)((tid & 3) ^ ((tid >> 3) & 3));
  const unsigned short* Ap = A + (long)z * sA + (bm + srow) * lda + schunk * 8;
  const unsigned short* Bp = Bm + (long)z * sB + (bn + srow) * ldb + schunk * 8;
  unsigned short* asd = As + tid * 8;
  unsigned short* bsd = Bs + tid * 8;
  const long a64 = 64 * lda;
  const long b64 = 64 * ldb;

  f32x4 acc[4][NW];
#pragma unroll
  for (int i = 0; i < 4; ++i)
#pragma unroll
    for (int j = 0; j < NW; ++j) acc[i][j] = (f32x4){0.f, 0.f, 0.f, 0.f};

  const int mo = (wave >> 1) * 64;
  const int no = (wave & 1) * (BN / 2);
  const int fr = lane & 15;
  const int fc = (((lane >> 4) ^ ((lane >> 1) & 3))) * 8;

  for (int k0 = 0; k0 < K; k0 += 64) {
    __syncthreads();
    gld16(Ap + k0, asd);
    gld16(Ap + a64 + k0, asd + 2048);
    gld16(Ap + k0 + 32, asd + 4096);
    gld16(Ap + a64 + k0 + 32, asd + 6144);
    gld16(Bp + k0, bsd);
    if (BN == 128) gld16(Bp + b64 + k0, bsd + 2048);
    gld16(Bp + k0 + 32, bsd + BSUB);
    if (BN == 128) gld16(Bp + b64 + k0 + 32, bsd + BSUB + 2048);
    __syncthreads();
#pragma unroll
    for (int ks = 0; ks < 2; ++ks) {
      bf16x8 af[4], bfr[NW];
#pragma unroll
      for (int i = 0; i < 4; ++i)
        af[i] = *(const bf16x8*)&As[ks * 4096 + (mo + i * 16 + fr) * 32 + fc];
#pragma unroll
      for (int i = 0; i < NW; ++i)
        bfr[i] = *(const bf16x8*)&Bs[ks * BSUB + (no + i * 16 + fr) * 32 + fc];
#pragma unroll
      for (int mi = 0; mi < 4; ++mi)
#pragma unroll
        for (int ni = 0; ni < NW; ++ni)
          acc[mi][ni] = __builtin_amdgcn_mfma_f32_16x16x32_bf16(af[mi], bfr[ni], acc[mi][ni], 0, 0, 0);
    }
  }

  const bool apply = !SPLITK || (z == 0);
  const long crow = bm + mo + ((lane >> 4) * 4);
  const long ccol = bn + no + (lane & 15);
#pragma unroll
  for (int mi = 0; mi < 4; ++mi) {
#pragma unroll
    for (int ni = 0; ni < NW; ++ni) {
      const long col = ccol + ni * 16;
      const float bv = (HAS_BIAS && apply) ? bias[col] : 0.f;
#pragma unroll
      for (int r = 0; r < 4; ++r) {
        const long row = crow + mi * 16 + r;
        float v = acc[mi][ni][r] * scale + bv;
        if (HAS_RES) { if (apply) v += res[row * ldr + col]; }
        if (RELU) v = fmaxf(v, 0.f);
        const long idxc = (long)z * sC + row * ldc + col;
        if (OUT_MODE == 0 || OUT_MODE == 2) ((float*)Cm)[idxc] = v;
        if (OUT_MODE == 1) ((unsigned short*)Cm)[idxc] = f2b(v);
        if (OUT_MODE == 2) C2[idxc] = f2b(v);
      }
    }
  }
}

#define GEMM_KERNEL(NAME, OM, RELU, HB, HR, BN, SK)                          \
  __global__ __launch_bounds__(256) void NAME(                               \
      const unsigned short* __restrict__ A, long lda, long sA,               \
      const unsigned short* __restrict__ Bm, long ldb, long sB,              \
      void* __restrict__ Cm, long ldc, long sC,                              \
      unsigned short* __restrict__ C2, const float* __restrict__ bias,       \
      const float* __restrict__ res, long ldr, float scale, int K) {         \
    gemm_bt_body<OM, RELU, HB, HR, BN, SK>(A, lda, sA, Bm, ldb, sB, Cm, ldc, \
                                           sC, C2, bias, res, ldr, scale, K);\
  }
GEMM_KERNEL(gemm_av, 2, 0, 0, 0, 64, 0)   // N=1024: BN=64 -> 1024 blocks, 4/CU

// ---------- row softmax over S, bf16 in (mask pre-added) -> bf16 out ----------
__global__ __launch_bounds__(256) void softmax_kernel(
    const unsigned short* __restrict__ Sb, unsigned short* __restrict__ Ab) {
  const long row = blockIdx.x;          // 0..MM-1
  const int tid = threadIdx.x;
  const unsigned short* sr = Sb + row * SS + tid * 8;
  bf16x8 sv = *(const bf16x8*)sr;
  float v[8];
  float mx = -1e30f;
#pragma unroll
  for (int i = 0; i < 8; ++i) {
    v[i] = b2f((unsigned short)sv[i]);
    mx = fmaxf(mx, v[i]);
  }
#pragma unroll
  for (int off = 32; off > 0; off >>= 1) mx = fmaxf(mx, __shfl_xor(mx, off, 64));
  __shared__ float rm[4], rs[4];
  if ((tid & 63) == 0) rm[tid >> 6] = mx;
  __syncthreads();
  mx = fmaxf(fmaxf(rm[0], rm[1]), fmaxf(rm[2], rm[3]));
  float sum = 0.f;
#pragma unroll
  for (int i = 0; i < 8; ++i) { v[i] = __expf(v[i] - mx); sum += v[i]; }
#pragma unroll
  for (int off = 32; off > 0; off >>= 1) sum += __shfl_xor(sum, off, 64);
  if ((tid & 63) == 0) rs[tid >> 6] = sum;
  __syncthreads();
  sum = rs[0] + rs[1] + rs[2] + rs[3];
  const float inv = 1.f / sum;
  bf16x8 ov;
#pragma unroll
  for (int i = 0; i < 8; ++i) ov[i] = (short)f2b(v[i] * inv);
  *(bf16x8*)(Ab + row * SS + tid * 8) = ov;
}

// ---------- in-place LayerNorm over H=1024, fused split-K partial add ----------
__global__ __launch_bounds__(256) void layernorm_kernel(
    float* __restrict__ Y, const float* __restrict__ P1,
    const float* __restrict__ g, const float* __restrict__ b) {
  const long row = blockIdx.x;
  float* y = Y + row * HH;
  const float* p1 = P1 + row * HH;
  const int tid = threadIdx.x;
  float v[4];
  float s = 0.f, ss = 0.f;
#pragma unroll
  for (int i = 0; i < 4; ++i) {
    v[i] = y[tid + i * 256] + p1[tid + i * 256];
    s += v[i]; ss += v[i] * v[i];
  }
#pragma unroll
  for (int off = 32; off > 0; off >>= 1) {
    s += __shfl_xor(s, off, 64);
    ss += __shfl_xor(ss, off, 64);
  }
  __shared__ float r1[4], r2[4];
  if ((tid & 63) == 0) { r1[tid >> 6] = s; r2[tid >> 6] = ss; }
  __syncthreads();
  s = r1[0] + r1[1] + r1[2] + r1[3];
  ss = r2[0] + r2[1] + r2[2] + r2[3];
  const float mu = s * (1.f / HH);
  const float var = ss * (1.f / HH) - mu * mu;
  const float rinv = rsqrtf(var + 1e-5f);
#pragma unroll
  for (int i = 0; i < 4; ++i) {
    int c = tid + i * 256;
    y[c] = (v[i] - mu) * rinv * g[c] + b[c];
  }
}

extern "C" void kernel_launch(void* const* d_in, const int* in_sizes, int n_in,
                              void* d_out, int out_size, void* d_ws, size_t ws_size,
                              hipStream_t stream) {
  (void)in_sizes; (void)n_in; (void)out_size; (void)ws_size;
  const float* x     = (const float*)d_in[0];
  const float* mask  = (const float*)d_in[1];
  const float* qW    = (const float*)d_in[2];
  const float* qb    = (const float*)d_in[3];
  const float* kW    = (const float*)d_in[4];
  const float* kb    = (const float*)d_in[5];
  const float* vW    = (const float*)d_in[6];
  const float* vb    = (const float*)d_in[7];
  const float* w1    = (const float*)d_in[8];
  const float* b1    = (const float*)d_in[9];
  const float* w2    = (const float*)d_in[10];
  const float* b2    = (const float*)d_in[11];
  const float* gamma = (const float*)d_in[12];
  const float* beta  = (const float*)d_in[13];
  float* out = (float*)d_out;

  char* ws = (char*)d_ws;
  size_t o = 0;
  auto alloc = [&](size_t bytes) { void* p = ws + o; o += (bytes + 255) & ~(size_t)255; return p; };
  unsigned short* Wqkv = (unsigned short*)alloc((size_t)3 * HH * HH * 2); // [3072][1024] (N,K) bf16
  unsigned short* w1t  = (unsigned short*)alloc((size_t)FF * HH * 2);     // [F][H]
  unsigned short* w2t  = (unsigned short*)alloc((size_t)HH * FF * 2);     // [H][F]
  float*          qkvb = (float*)alloc((size_t)3 * HH * 4);               // concat bias
  unsigned short* xb   = (unsigned short*)alloc((size_t)MM * HH * 2);     // x bf16
  unsigned short* QKVb = (unsigned short*)alloc((size_t)MM * 3 * HH * 2); // [M,3072] bf16
  unsigned short* Vt   = (unsigned short*)alloc((size_t)HH * MM * 2);     // [H][M] V^T bf16
  float*          attnf= (float*)alloc((size_t)MM * HH * 4);              // attn fp32 (residual)
  unsigned short* attnb= (unsigned short*)alloc((size_t)MM * HH * 2);     // attn bf16
  unsigned short* Sb   = (unsigned short*)alloc((size_t)BB * SS * SS * 4);// scores bf16 (over-alloc; tail reused as hb)
  unsigned short* Ab   = (unsigned short*)alloc((size_t)BB * SS * SS * 2);
  unsigned short* hb   = Sb + (size_t)BB * SS * SS;  // [M,F] bf16; Sb dead by FFN1 time
  // ffn2 split-K partial #1: QKVb region is dead after gemm_qk/av (48 MB >= 32 MB)
  float*          part1= (float*)QKVb;

  const dim3 tb(32, 8);

  // 1. x -> bf16
  conv_f2b_kernel<<<MM * HH / 1024, 256, 0, stream>>>(x, xb, (long)MM * HH / 4);
  // 2. weight transposes (fp32 [K,N] -> bf16 [N,K]); QKV concatenated along N
  transpose_f2b_kernel<<<dim3(HH / 32, HH / 32), tb, 0, stream>>>(qW, Wqkv, HH, HH);
  transpose_f2b_kernel<<<dim3(HH / 32, HH / 32), tb, 0, stream>>>(kW, Wqkv + (size_t)HH * HH, HH, HH);
  transpose_f2b_kernel<<<dim3(HH / 32, HH / 32), tb, 0, stream>>>(vW, Wqkv + (size_t)2 * HH * HH, HH, HH);
  transpose_f2b_kernel<<<dim3(FF / 32, HH / 32), tb, 0, stream>>>(w1, w1t, HH, FF);
  transpose_f2b_kernel<<<dim3(HH / 32, FF / 32), tb, 0, stream>>>(w2, w2t, FF, HH);
  concat3_kernel<<<12, 256, 0, stream>>>(qb, kb, vb, qkvb);
  // 3. QKV = x * Wqkv^T + b, single 256^2 pipelined GEMM, bf16 out [M,3072]
  gemm_qkv<<<dim3(3 * HH / 256, MM / 256, 1), 512, 0, stream>>>(
      xb, HH, 0, Wqkv, HH, 0, QKVb, 3 * HH, 0, nullptr, qkvb, nullptr, 0, 1.f, HH);
  // 4. V^T (bf16 [M,1024] slice of QKVb -> bf16 [1024,M])
  transpose_b2b_kernel<<<dim3(HH / 32, MM / 32), tb, 0, stream>>>(
      QKVb + 2 * HH, 3 * HH, Vt, MM, HH);
  // 5. S = Q K^T / sqrt(H) + mask, batched over BB, bf16 out
  gemm_qk<<<dim3(SS / 256, SS / 256, BB), 512, 0, stream>>>(
      QKVb, 3 * HH, (long)SS * 3 * HH, QKVb + HH, 3 * HH, (long)SS * 3 * HH,
      Sb, SS, (long)SS * SS, nullptr, nullptr, mask, SS, 0.03125f, HH);
  // 6. A = softmax(S) -> bf16
  softmax_kernel<<<MM, 256, 0, stream>>>(Sb, Ab);
  // 7. attn = A V, batched; fp32 + bf16 dual output (old 128x64 kernel)
  gemm_av<<<dim3(HH / 64, SS / 128, BB), 256, 0, stream>>>(
      Ab, SS, (long)SS * SS, Vt, MM, SS, attnf, HH, (long)SS * HH,
      attnb, nullptr, nullptr, 0, 1.f, SS);
  // 8. h = relu(attn w1 + b1) -> bf16, 256^2 pipelined
  gemm_ffn1<<<dim3(FF / 256, MM / 256, 1), 512, 0, stream>>>(
      attnb, HH, 0, w1t, HH, 0, hb, FF, 0, nullptr, b1, nullptr, 0, 1.f, HH);
  // 9. y_partial = attn + h[:,z] w2[z,:] + b2 ; 256^2 pipelined, split-K=2
  gemm_ffn2<<<dim3(HH / 256, MM / 256, 2), 512, 0, stream>>>(
      hb, FF, (long)(FF / 2), w2t, FF, (long)(FF / 2),
      out, HH, (long)((float*)part1 - out),
      nullptr, b2, attnf, HH, 1.f, FF / 2);
  // 10. LayerNorm in place, fusing the split-K partial sum
  layernorm_kernel<<<MM, 256, 0, stream>>>(out, part1, gamma, beta);
}